// Round 1
// baseline (237.765 us; speedup 1.0000x reference)
//
#include <hip/hip_runtime.h>

#define NC 14
#define DIM 96
#define NV (DIM*DIM*DIM)   // 884736

// ---------------- Kernel 1: per-voxel argmax over class dim ----------------
__global__ void argmax_kernel(const float* __restrict__ outT,
                              unsigned char* __restrict__ tgt) {
    int idx = blockIdx.x * blockDim.x + threadIdx.x;
    const int total = 2 * NV;
    if (idx >= total) return;
    int b = idx / NV;
    int v = idx - b * NV;
    const float* p = outT + (size_t)b * NC * NV + v;
    float best = p[0];
    int bi = 0;
#pragma unroll
    for (int c = 1; c < NC; ++c) {
        float val = p[(size_t)c * NV];
        if (val > best) { best = val; bi = c; }
    }
    tgt[idx] = (unsigned char)bi;
}

// ------- Kernel 2: boundary mask + per-voxel KL + hierarchical reduce -------
__global__ void __launch_bounds__(256)
boundary_kl_kernel(const float* __restrict__ pS, const float* __restrict__ pT,
                   const unsigned char* __restrict__ tgt,
                   float* __restrict__ acc_num, unsigned int* __restrict__ acc_n) {
    const int b = blockIdx.x & 1;
    const int blocksPerB = gridDim.x >> 1;
    const int bslot = blockIdx.x >> 1;

    const unsigned char* __restrict__ t = tgt + b * NV;
    const float* __restrict__ sS = pS + (size_t)b * NC * NV;
    const float* __restrict__ sT = pT + (size_t)b * NC * NV;

    float numacc[NC];
    unsigned int nacc[NC];
#pragma unroll
    for (int c = 0; c < NC; ++c) { numacc[c] = 0.f; nacc[c] = 0u; }

    for (int v = bslot * blockDim.x + threadIdx.x; v < NV;
         v += blocksPerB * blockDim.x) {
        int d = v % DIM;
        int w = (v / DIM) % DIM;
        int h = v / (DIM * DIM);

        // 14-bit mask of classes present in the in-bounds 3x3x3 neighborhood
        unsigned mask = 0;
#pragma unroll
        for (int dh = -1; dh <= 1; ++dh) {
            int hh = h + dh;
            if ((unsigned)hh >= DIM) continue;
#pragma unroll
            for (int dw = -1; dw <= 1; ++dw) {
                int ww = w + dw;
                if ((unsigned)ww >= DIM) continue;
                int base = (hh * DIM + ww) * DIM + d;
#pragma unroll
                for (int dd = -1; dd <= 1; ++dd) {
                    int ddd = d + dd;
                    if ((unsigned)ddd >= DIM) continue;
                    mask |= 1u << t[base + dd];
                }
            }
        }

        bool interior = (h >= 1 && h <= DIM - 2 && w >= 1 && w <= DIM - 2 &&
                         d >= 1 && d <= DIM - 2);
        // fully interior + uniform window -> box-sum == 27 -> no boundary class
        if (interior && (mask & (mask - 1)) == 0) continue;

        // per-voxel KL: sum_c exp(lt_c) * (lt_c - ls_c), log-softmax over classes
        float vs[NC], vt[NC];
        float maxS = -1e30f, maxT = -1e30f;
#pragma unroll
        for (int c = 0; c < NC; ++c) {
            vs[c] = sS[(size_t)c * NV + v];
            vt[c] = sT[(size_t)c * NV + v];
            maxS = fmaxf(maxS, vs[c]);
            maxT = fmaxf(maxT, vt[c]);
        }
        float seS = 0.f, seT = 0.f;
#pragma unroll
        for (int c = 0; c < NC; ++c) {
            seS += __expf(vs[c] - maxS);
            seT += __expf(vt[c] - maxT);
        }
        float lseS = __logf(seS), lseT = __logf(seT);
        float pk = 0.f;
#pragma unroll
        for (int c = 0; c < NC; ++c) {
            float lt = vt[c] - maxT - lseT;
            float ls = vs[c] - maxS - lseS;
            pk += __expf(lt) * (lt - ls);
        }

        unsigned m = mask;
        while (m) {
            int k = __ffs(m) - 1;
            m &= m - 1;
            numacc[k] += pk;
            nacc[k] += 1u;
        }
    }

    // block reduction: registers -> LDS -> global atomics
    __shared__ float snum[NC];
    __shared__ unsigned int sn[NC];
    if (threadIdx.x < NC) { snum[threadIdx.x] = 0.f; sn[threadIdx.x] = 0u; }
    __syncthreads();
#pragma unroll
    for (int c = 0; c < NC; ++c) {
        if (nacc[c]) {
            atomicAdd(&snum[c], numacc[c]);
            atomicAdd(&sn[c], nacc[c]);
        }
    }
    __syncthreads();
    if (threadIdx.x < NC) {
        if (sn[threadIdx.x]) {
            atomicAdd(&acc_num[b * NC + threadIdx.x], snum[threadIdx.x]);
            atomicAdd(&acc_n[b * NC + threadIdx.x], sn[threadIdx.x]);
        }
    }
}

// ---------------- Kernel 3: finalize scalar ----------------
__global__ void finalize_kernel(const float* __restrict__ acc_num,
                                const unsigned int* __restrict__ acc_n,
                                float* __restrict__ out) {
    if (threadIdx.x == 0 && blockIdx.x == 0) {
        float s = 0.f;
        for (int i = 0; i < 2 * NC; ++i) {
            unsigned int n = acc_n[i];
            if (n > 0u) s += acc_num[i] / ((float)NC * (float)n);
        }
        out[0] = s;
    }
}

extern "C" void kernel_launch(void* const* d_in, const int* in_sizes, int n_in,
                              void* d_out, int out_size, void* d_ws, size_t ws_size,
                              hipStream_t stream) {
    const float* preds_S = (const float*)d_in[0];
    const float* preds_T = (const float*)d_in[1];
    const float* outputs_T = (const float*)d_in[2];

    // workspace layout: [32 floats acc_num][32 uints acc_n][2*NV bytes targets]
    float* acc_num = (float*)d_ws;
    unsigned int* acc_n = (unsigned int*)(acc_num + 32);
    unsigned char* tgt = (unsigned char*)(acc_n + 32);

    hipMemsetAsync(d_ws, 0, 256, stream);

    {
        int total = 2 * NV;
        int threads = 256;
        int blocks = (total + threads - 1) / threads;
        argmax_kernel<<<blocks, threads, 0, stream>>>(outputs_T, tgt);
    }
    {
        int blocks = 2048;  // even: low bit selects batch
        boundary_kl_kernel<<<blocks, 256, 0, stream>>>(preds_S, preds_T, tgt,
                                                       acc_num, acc_n);
    }
    finalize_kernel<<<1, 64, 0, stream>>>(acc_num, acc_n, (float*)d_out);
}

// Round 2
// 143.499 us; speedup vs baseline: 1.6569x; 1.6569x over previous
//
#include <hip/hip_runtime.h>

#define NC 14
#define DIM 96
#define NV (DIM*DIM*DIM)     // 884736
#define PD 98
#define PSLICE (PD*PD)       // 9604
#define PADV (PD*PD*PD)      // 941192
#define SLAB 3764992         // PADV*2(batches)*2(bytes) rounded up to 256

// ---- Kernel 1: per-voxel argmax -> 1<<class bitmask into padded volume ----
__global__ void argmax_bit_kernel(const float* __restrict__ outT,
                                  unsigned short* __restrict__ bm) {
    int idx = blockIdx.x * blockDim.x + threadIdx.x;
    if (idx >= 2 * NV) return;
    int b = idx / NV;
    int v = idx - b * NV;
    const float* p = outT + (size_t)b * NC * NV + v;
    float best = p[0];
    int bi = 0;
#pragma unroll
    for (int c = 1; c < NC; ++c) {
        float val = p[(size_t)c * NV];
        if (val > best) { best = val; bi = c; }
    }
    int d = v % DIM;
    int t1 = v / DIM;
    int w = t1 % DIM;
    int h = t1 / DIM;
    bm[(size_t)b * PADV + (h + 1) * PSLICE + (w + 1) * PD + (d + 1)] =
        (unsigned short)(1u << bi);
}

// ---- Kernel 2: OR along d (pad stays 0) ----
__global__ void or_d_kernel(const unsigned short* __restrict__ bm,
                            unsigned short* __restrict__ dm) {
    int p = blockIdx.x * blockDim.x + threadIdx.x;
    if (p >= 2 * PADV) return;
    int pd = (p % PADV) % PD;
    if (pd < 1 || pd > DIM) return;
    dm[p] = (unsigned short)(bm[p - 1] | bm[p] | bm[p + 1]);
}

// ---- Kernel 3: OR along w ----
__global__ void or_w_kernel(const unsigned short* __restrict__ dm,
                            unsigned short* __restrict__ wm) {
    int p = blockIdx.x * blockDim.x + threadIdx.x;
    if (p >= 2 * PADV) return;
    int pw = ((p % PADV) / PD) % PD;
    if (pw < 1 || pw > DIM) return;
    wm[p] = (unsigned short)(dm[p - PD] | dm[p] | dm[p + PD]);
}

// ---- Kernel 4: final OR along h + KL + static-indexed accumulation ----
__global__ void __launch_bounds__(256)
boundary_kl_kernel(const float* __restrict__ pS, const float* __restrict__ pT,
                   const unsigned short* __restrict__ wm,
                   float* __restrict__ acc_num, float* __restrict__ acc_cnt) {
    const int b = blockIdx.x & 1;
    const int blocksPerB = gridDim.x >> 1;
    const int bslot = blockIdx.x >> 1;

    const float* __restrict__ sS = pS + (size_t)b * NC * NV;
    const float* __restrict__ sT = pT + (size_t)b * NC * NV;
    const unsigned short* __restrict__ w0 = wm + (size_t)b * PADV;

    float numacc[NC], nacc[NC];
#pragma unroll
    for (int c = 0; c < NC; ++c) { numacc[c] = 0.f; nacc[c] = 0.f; }

    for (int v = bslot * 256 + threadIdx.x; v < NV; v += blocksPerB * 256) {
        int d = v % DIM;
        int t1 = v / DIM;
        int w = t1 % DIM;
        int h = t1 / DIM;
        int pb = (h + 1) * PSLICE + (w + 1) * PD + (d + 1);

        unsigned mask = (unsigned)w0[pb - PSLICE] | (unsigned)w0[pb] |
                        (unsigned)w0[pb + PSLICE];

        bool interior = ((unsigned)(h - 1) <= 93u) && ((unsigned)(w - 1) <= 93u) &&
                        ((unsigned)(d - 1) <= 93u);
        // fully-interior uniform window -> box-sum == 27 -> no boundary class
        unsigned emask = (interior && (mask & (mask - 1)) == 0u) ? 0u : mask;

        float vs[NC], vt[NC];
        float maxS = -1e30f, maxT = -1e30f;
#pragma unroll
        for (int c = 0; c < NC; ++c) {
            vs[c] = sS[(size_t)c * NV + v];
            vt[c] = sT[(size_t)c * NV + v];
            maxS = fmaxf(maxS, vs[c]);
            maxT = fmaxf(maxT, vt[c]);
        }
        float seS = 0.f, seT = 0.f, dot = 0.f;
#pragma unroll
        for (int c = 0; c < NC; ++c) {
            seS += __expf(vs[c] - maxS);
            float e = __expf(vt[c] - maxT);
            seT += e;
            dot += e * (vt[c] - vs[c]);
        }
        // pk = sum_c pT_c*(vt_c-vs_c) + (maxS+lseS) - (maxT+lseT)
        float pk = dot / seT + (maxS - maxT) + __logf(seS) - __logf(seT);

#pragma unroll
        for (int c = 0; c < NC; ++c) {
            bool hit = (emask >> c) & 1u;
            numacc[c] += hit ? pk : 0.f;
            nacc[c] += hit ? 1.f : 0.f;
        }
    }

    // wave shfl reduction -> LDS -> global atomics
    __shared__ float snum[NC], scnt[NC];
    if (threadIdx.x < NC) { snum[threadIdx.x] = 0.f; scnt[threadIdx.x] = 0.f; }
    __syncthreads();
    int lane = threadIdx.x & 63;
#pragma unroll
    for (int c = 0; c < NC; ++c) {
        float s = numacc[c], n = nacc[c];
#pragma unroll
        for (int o = 32; o; o >>= 1) {
            s += __shfl_xor(s, o);
            n += __shfl_xor(n, o);
        }
        if (lane == 0) {
            atomicAdd(&snum[c], s);
            atomicAdd(&scnt[c], n);
        }
    }
    __syncthreads();
    if (threadIdx.x < NC) {
        atomicAdd(&acc_num[b * NC + threadIdx.x], snum[threadIdx.x]);
        atomicAdd(&acc_cnt[b * NC + threadIdx.x], scnt[threadIdx.x]);
    }
}

// ---- Kernel 5: finalize scalar ----
__global__ void finalize_kernel(const float* __restrict__ acc_num,
                                const float* __restrict__ acc_cnt,
                                float* __restrict__ out) {
    if (threadIdx.x == 0 && blockIdx.x == 0) {
        float s = 0.f;
        for (int i = 0; i < 2 * NC; ++i) {
            float n = acc_cnt[i];
            if (n > 0.f) s += acc_num[i] / ((float)NC * n);
        }
        out[0] = s;
    }
}

extern "C" void kernel_launch(void* const* d_in, const int* in_sizes, int n_in,
                              void* d_out, int out_size, void* d_ws, size_t ws_size,
                              hipStream_t stream) {
    const float* preds_S = (const float*)d_in[0];
    const float* preds_T = (const float*)d_in[1];
    const float* outputs_T = (const float*)d_in[2];

    // workspace layout (all 256-aligned):
    // [0,256)                : acc_num (32 floats) + acc_cnt (32 floats)
    // [256, 256+SLAB)        : bm  padded bitmask
    // [256+SLAB, 256+2*SLAB) : dm  d-OR
    // [256+2*SLAB, 256+3*SLAB): wm w-OR
    char* ws = (char*)d_ws;
    float* acc_num = (float*)ws;
    float* acc_cnt = acc_num + 32;
    unsigned short* bm = (unsigned short*)(ws + 256);
    unsigned short* dm = (unsigned short*)(ws + 256 + (size_t)SLAB);
    unsigned short* wm = (unsigned short*)(ws + 256 + 2 * (size_t)SLAB);

    hipMemsetAsync(d_ws, 0, 256 + 3 * (size_t)SLAB, stream);

    {
        int blocks = (2 * NV + 255) / 256;
        argmax_bit_kernel<<<blocks, 256, 0, stream>>>(outputs_T, bm);
    }
    {
        int blocks = (2 * PADV + 255) / 256;
        or_d_kernel<<<blocks, 256, 0, stream>>>(bm, dm);
        or_w_kernel<<<blocks, 256, 0, stream>>>(dm, wm);
    }
    {
        // 1728 blocks per batch: each thread handles exactly 2 voxels
        boundary_kl_kernel<<<3456, 256, 0, stream>>>(preds_S, preds_T, wm,
                                                     acc_num, acc_cnt);
    }
    finalize_kernel<<<1, 64, 0, stream>>>(acc_num, acc_cnt, (float*)d_out);
}

// Round 3
// 94.241 us; speedup vs baseline: 2.5229x; 1.5227x over previous
//
#include <hip/hip_runtime.h>

#define NC 14
#define DIM 96
#define NV (DIM*DIM*DIM)       // 884736
// padded mask volume: inner (d) stride 104, d stored at +4; w,h stored at +1
#define WS 104
#define HS (104*98)            // 10192
#define PADV2 (104*98*98)      // 998816 elements per batch
#define SLABB ((size_t)PADV2*2*2)  // bytes for 2 batches of ushort = 3995264

// ---- Kernel 1: argmax over classes for 4 voxels -> bitmask ushort4 ----
__global__ void __launch_bounds__(256)
argmax_bit_kernel(const float* __restrict__ outT, unsigned short* __restrict__ bm) {
    int tid = blockIdx.x * 256 + threadIdx.x;
    if (tid >= 2 * (NV / 4)) return;
    int b = tid >= (NV / 4);
    int q = tid - b * (NV / 4);
    int v4 = q * 4;
    const float* p = outT + (size_t)b * NC * NV + v4;
    float4 best = *(const float4*)p;
    int bx = 0, by = 0, bz = 0, bw = 0;
#pragma unroll
    for (int c = 1; c < NC; ++c) {
        float4 val = *(const float4*)(p + (size_t)c * NV);
        if (val.x > best.x) { best.x = val.x; bx = c; }
        if (val.y > best.y) { best.y = val.y; by = c; }
        if (val.z > best.z) { best.z = val.z; bz = c; }
        if (val.w > best.w) { best.w = val.w; bw = c; }
    }
    int d = v4 % DIM;
    int t1 = v4 / DIM;
    int w = t1 % DIM;
    int h = t1 / DIM;
    ushort4 out;
    out.x = (unsigned short)(1u << bx);
    out.y = (unsigned short)(1u << by);
    out.z = (unsigned short)(1u << bz);
    out.w = (unsigned short)(1u << bw);
    *(ushort4*)(bm + (size_t)b * PADV2 + (h + 1) * HS + (w + 1) * WS + (d + 4)) = out;
}

// ---- Kernel 2: OR along d ----
__global__ void or_d_kernel(const unsigned short* __restrict__ bm,
                            unsigned short* __restrict__ dm) {
    int p = blockIdx.x * blockDim.x + threadIdx.x;
    if (p >= 2 * PADV2) return;
    int pd = (p % PADV2) % WS;
    if (pd < 4 || pd > 99) return;
    dm[p] = (unsigned short)(bm[p - 1] | bm[p] | bm[p + 1]);
}

// ---- Kernel 3: OR along w ----
__global__ void or_w_kernel(const unsigned short* __restrict__ dm,
                            unsigned short* __restrict__ wm) {
    int p = blockIdx.x * blockDim.x + threadIdx.x;
    if (p >= 2 * PADV2) return;
    int pw = ((p % PADV2) / WS) % 98;
    if (pw < 1 || pw > 96) return;
    wm[p] = (unsigned short)(dm[p - WS] | dm[p] | dm[p + WS]);
}

// ---- Kernel 4: h-OR + KL (no max-sub) + static accumulation, 4 voxels/thread ----
__global__ void __launch_bounds__(256)
boundary_kl_kernel(const float* __restrict__ pS, const float* __restrict__ pT,
                   const unsigned short* __restrict__ wm,
                   float* __restrict__ acc_num, float* __restrict__ acc_cnt) {
    const int b = blockIdx.x & 1;
    const int bslot = blockIdx.x >> 1;
    int tid4 = bslot * 256 + threadIdx.x;          // < NV/4
    int v4 = tid4 * 4;
    int d = v4 % DIM;                               // multiple of 4
    int t1 = v4 / DIM;
    int w = t1 % DIM;
    int h = t1 / DIM;

    const float* sS = pS + (size_t)b * NC * NV + v4;
    const float* sT = pT + (size_t)b * NC * NV + v4;
    const unsigned short* w0 = wm + (size_t)b * PADV2;

    int off = (h + 1) * HS + (w + 1) * WS + (d + 4);
    ushort4 m0 = *(const ushort4*)(w0 + off - HS);
    ushort4 m1 = *(const ushort4*)(w0 + off);
    ushort4 m2 = *(const ushort4*)(w0 + off + HS);

    float4 seS = {0.f, 0.f, 0.f, 0.f};
    float4 seT = {0.f, 0.f, 0.f, 0.f};
    float4 dot = {0.f, 0.f, 0.f, 0.f};
#pragma unroll
    for (int c = 0; c < NC; ++c) {
        float4 vs = *(const float4*)(sS + (size_t)c * NV);
        float4 vt = *(const float4*)(sT + (size_t)c * NV);
        float e;
        seS.x += __expf(vs.x); e = __expf(vt.x); seT.x += e; dot.x += e * (vt.x - vs.x);
        seS.y += __expf(vs.y); e = __expf(vt.y); seT.y += e; dot.y += e * (vt.y - vs.y);
        seS.z += __expf(vs.z); e = __expf(vt.z); seT.z += e; dot.z += e * (vt.z - vs.z);
        seS.w += __expf(vs.w); e = __expf(vt.w); seT.w += e; dot.w += e * (vt.w - vs.w);
    }
    float pk[4];
    pk[0] = dot.x / seT.x + __logf(seS.x) - __logf(seT.x);
    pk[1] = dot.y / seT.y + __logf(seS.y) - __logf(seT.y);
    pk[2] = dot.z / seT.z + __logf(seS.z) - __logf(seT.z);
    pk[3] = dot.w / seT.w + __logf(seS.w) - __logf(seT.w);

    unsigned mk[4];
    mk[0] = (unsigned)(m0.x | m1.x | m2.x);
    mk[1] = (unsigned)(m0.y | m1.y | m2.y);
    mk[2] = (unsigned)(m0.z | m1.z | m2.z);
    mk[3] = (unsigned)(m0.w | m1.w | m2.w);

    bool hwint = ((unsigned)(h - 1) <= 93u) && ((unsigned)(w - 1) <= 93u);
    float num[NC], cnt[NC];
#pragma unroll
    for (int c = 0; c < NC; ++c) { num[c] = 0.f; cnt[c] = 0.f; }
#pragma unroll
    for (int j = 0; j < 4; ++j) {
        bool interior = hwint && ((unsigned)(d + j - 1) <= 93u);
        unsigned m = mk[j];
        if (interior && (m & (m - 1)) == 0u) m = 0u;   // uniform interior window
        float p = pk[j];
#pragma unroll
        for (int c = 0; c < NC; ++c) {
            float hit = (float)((m >> c) & 1u);
            num[c] = fmaf(hit, p, num[c]);
            cnt[c] += hit;
        }
    }

    // wave shfl reduction -> LDS -> global atomics
    __shared__ float snum[NC], scnt[NC];
    if (threadIdx.x < NC) { snum[threadIdx.x] = 0.f; scnt[threadIdx.x] = 0.f; }
    __syncthreads();
    int lane = threadIdx.x & 63;
#pragma unroll
    for (int c = 0; c < NC; ++c) {
        float s = num[c], n = cnt[c];
#pragma unroll
        for (int o = 32; o; o >>= 1) {
            s += __shfl_xor(s, o);
            n += __shfl_xor(n, o);
        }
        if (lane == 0) {
            atomicAdd(&snum[c], s);
            atomicAdd(&scnt[c], n);
        }
    }
    __syncthreads();
    if (threadIdx.x < NC) {
        atomicAdd(&acc_num[b * NC + threadIdx.x], snum[threadIdx.x]);
        atomicAdd(&acc_cnt[b * NC + threadIdx.x], scnt[threadIdx.x]);
    }
}

// ---- Kernel 5: finalize scalar ----
__global__ void finalize_kernel(const float* __restrict__ acc_num,
                                const float* __restrict__ acc_cnt,
                                float* __restrict__ out) {
    if (threadIdx.x == 0 && blockIdx.x == 0) {
        float s = 0.f;
        for (int i = 0; i < 2 * NC; ++i) {
            float n = acc_cnt[i];
            if (n > 0.f) s += acc_num[i] / ((float)NC * n);
        }
        out[0] = s;
    }
}

extern "C" void kernel_launch(void* const* d_in, const int* in_sizes, int n_in,
                              void* d_out, int out_size, void* d_ws, size_t ws_size,
                              hipStream_t stream) {
    const float* preds_S = (const float*)d_in[0];
    const float* preds_T = (const float*)d_in[1];
    const float* outputs_T = (const float*)d_in[2];

    // ws layout: [256B acc][bm SLABB][dm SLABB][wm SLABB]
    char* ws = (char*)d_ws;
    float* acc_num = (float*)ws;
    float* acc_cnt = acc_num + 32;
    unsigned short* bm = (unsigned short*)(ws + 256);
    unsigned short* dm = (unsigned short*)(ws + 256 + SLABB);
    unsigned short* wm = (unsigned short*)(ws + 256 + 2 * SLABB);

    hipMemsetAsync(d_ws, 0, 256 + 3 * SLABB, stream);

    {
        int threadsTotal = 2 * (NV / 4);              // 442368
        argmax_bit_kernel<<<(threadsTotal + 255) / 256, 256, 0, stream>>>(outputs_T, bm);
    }
    {
        int total = 2 * PADV2;
        int blocks = (total + 255) / 256;
        or_d_kernel<<<blocks, 256, 0, stream>>>(bm, dm);
        or_w_kernel<<<blocks, 256, 0, stream>>>(dm, wm);
    }
    {
        // 864 blocks per batch * 2, low bit of blockIdx selects batch
        boundary_kl_kernel<<<1728, 256, 0, stream>>>(preds_S, preds_T, wm,
                                                     acc_num, acc_cnt);
    }
    finalize_kernel<<<1, 64, 0, stream>>>(acc_num, acc_cnt, (float*)d_out);
}